// Round 5
// baseline (212.128 us; speedup 1.0000x reference)
//
#include <hip/hip_runtime.h>

#define B_ 64
#define NB_ 8
#define Q_ 32
#define T_ 256
#define D_ 256
#define NBINS 11

typedef __attribute__((ext_vector_type(8))) short bf16x8;
typedef __attribute__((ext_vector_type(4))) float f32x4;
typedef unsigned short ushort_t;
typedef unsigned int uint_t;

// ws byte offsets (fast path): fragment-ordered bf16 hi/lo splits + psum
#define CANH_OFF 0u
#define CANL_OFF 8388608u
#define HQH_OFF 16777216u
#define HQL_OFF 25165824u
#define PSUM_OFF 33554432u
#define WS_NEED (33554432u + 720896u)

__device__ inline ushort_t bf16_rnd(float f) {
  uint_t u = __float_as_uint(f);
  return (ushort_t)((u + 0x8000u) >> 16);
}
__device__ inline uint_t pack2(ushort_t a, ushort_t b) {
  return (uint_t)a | ((uint_t)b << 16);
}

// ---------------------------------------------------------------------------
// split_kernel: normalize rows and split fp32 -> (bf16 hi, bf16 lo), storing
// in MFMA-fragment order: frag(tile, kk) elem for lane l =
//   X[tile*16 + (l&15)][kk*32 + (l>>4)*8 + j],  j=0..7 contiguous (16 B/lane).
// Blocks 0..511: can (b, 32-row chunk). Blocks 512..1023: hq (outb, 32 rows).
// Phase 1 = R4's validated staging (coalesced load, 32-lane shfl norm, split)
// into LDS; phase 2 = fragment gather from LDS -> coalesced global store.
// ---------------------------------------------------------------------------
__global__ __launch_bounds__(256) void split_kernel(
    const float* __restrict__ can, const float* __restrict__ hq,
    uint4* __restrict__ canH, uint4* __restrict__ canL,
    uint4* __restrict__ hqH, uint4* __restrict__ hqL) {
  __shared__ __align__(16) ushort_t sm_hi[32 * 264];
  __shared__ __align__(16) ushort_t sm_lo[32 * 264];
  int blk = blockIdx.x;
  int tid = threadIdx.x;
  const float* src;
  uint4 *dH, *dL;
  int tilebase;
  if (blk < 512) {
    int b = blk >> 3, ch = blk & 7;
    src = can + ((size_t)b * T_ + ch * 32) * D_;
    tilebase = b * 16 + ch * 2;
    dH = canH;
    dL = canL;
  } else {
    int outb = blk - 512;
    src = hq + (size_t)outb * Q_ * D_;
    tilebase = outb * 2;
    dH = hqH;
    dL = hqL;
  }
#pragma unroll
  for (int it = 0; it < 4; it++) {
    int flat = it * 2048 + tid * 8;
    int row = flat >> 8, col = flat & 255;
    const float* p = src + row * D_ + col;
    float4 x = reinterpret_cast<const float4*>(p)[0];
    float4 y = reinterpret_cast<const float4*>(p)[1];
    float s = x.x * x.x + x.y * x.y + x.z * x.z + x.w * x.w +
              y.x * y.x + y.y * y.y + y.z * y.z + y.w * y.w;
    // 32 consecutive threads cover one 256-col row
    s += __shfl_xor(s, 1);
    s += __shfl_xor(s, 2);
    s += __shfl_xor(s, 4);
    s += __shfl_xor(s, 8);
    s += __shfl_xor(s, 16);
    float inv = 1.0f / fmaxf(sqrtf(s), 1e-10f);
    float v[8] = {x.x, x.y, x.z, x.w, y.x, y.y, y.z, y.w};
    ushort_t h[8], l[8];
#pragma unroll
    for (int j = 0; j < 8; j++) {
      float sv = v[j] * inv;
      h[j] = bf16_rnd(sv);
      float hf = __uint_as_float(((uint_t)h[j]) << 16);
      l[j] = bf16_rnd(sv - hf);
    }
    uint4 ph = {pack2(h[0], h[1]), pack2(h[2], h[3]), pack2(h[4], h[5]),
                pack2(h[6], h[7])};
    uint4 pl = {pack2(l[0], l[1]), pack2(l[2], l[3]), pack2(l[4], l[5]),
                pack2(l[6], l[7])};
    *reinterpret_cast<uint4*>(&sm_hi[row * 264 + col]) = ph;
    *reinterpret_cast<uint4*>(&sm_lo[row * 264 + col]) = pl;
  }
  __syncthreads();
  int wv = tid >> 6, lane = tid & 63;
  int tl = wv >> 1, part = wv & 1;  // tile-local 0/1, hi/lo part
  int lq = lane & 15, lk = lane >> 4;
  const ushort_t* smp = part ? sm_lo : sm_hi;
  uint4* dst = part ? dL : dH;
#pragma unroll
  for (int kk = 0; kk < 8; kk++) {
    const ushort_t* a = &smp[(tl * 16 + lq) * 264 + kk * 32 + lk * 8];
    dst[((size_t)(tilebase + tl) * 8 + kk) * 64 + lane] =
        *reinterpret_cast<const uint4*>(a);
  }
}

// ---------------------------------------------------------------------------
// pool_kernel (fast path): grid = 2048 = b(64) x nb(8) x tq(4). No LDS, no
// barriers. Wave = (mtile 16q, 32-t half of the 64-t quarter). A-frags and
// B-frags loaded directly global->VGPR from fragment-ordered ws (coalesced
// 1 KiB per wave-load, L2-hot: XCD swizzle keeps all blocks of b on XCD b%8).
// Split-bf16 3-MFMA (validated R4); Gaussian bins; shfl-reduce over 16 t;
// atomicAdd into psum[outb][q][11].
// ---------------------------------------------------------------------------
__global__ __launch_bounds__(256) void pool_kernel(
    const uint4* __restrict__ canH, const uint4* __restrict__ canL,
    const uint4* __restrict__ hqH, const uint4* __restrict__ hqL,
    const float* __restrict__ mask_can, float* __restrict__ psum) {
  const float mus[NBINS] = {1.0f, 0.9f, 0.7f, 0.5f, 0.3f, 0.1f,
                            -0.1f, -0.3f, -0.5f, -0.7f, -0.9f};
  const float nis2[NBINS] = {-5.0e5f, -50.f, -50.f, -50.f, -50.f, -50.f,
                             -50.f, -50.f, -50.f, -50.f, -50.f};
  int i = blockIdx.x;
  int b = i & 63;          // XCD = i%8 = b%8 -> can slice stays in one L2
  int nb = (i >> 6) & 7;
  int tq = i >> 9;         // 0..3, 64-t quarter
  int outb = b * NB_ + nb;
  int tid = threadIdx.x;
  int wv = tid >> 6, lane = tid & 63;
  int lq = lane & 15, lk = lane >> 4;
  int mtile = wv >> 1, th = wv & 1;

  // A fragments (one mtile = 16 q-rows), 16 coalesced 16B loads
  bf16x8 ah[8], al[8];
  {
    size_t abase = (size_t)(outb * 2 + mtile) * 8 * 64 + lane;
#pragma unroll
    for (int kk = 0; kk < 8; kk++) {
      ah[kk] = *reinterpret_cast<const bf16x8*>(&hqH[abase + kk * 64]);
      al[kk] = *reinterpret_cast<const bf16x8*>(&hqL[abase + kk * 64]);
    }
  }

  float binacc[4][NBINS];
#pragma unroll
  for (int r = 0; r < 4; r++)
#pragma unroll
    for (int j = 0; j < NBINS; j++) binacc[r][j] = 0.0f;

#pragma unroll
  for (int ti = 0; ti < 2; ti++) {
    int tt = tq * 4 + th * 2 + ti;  // global 16-t tile index, 0..15
    size_t bbase = (size_t)(b * 16 + tt) * 8 * 64 + lane;
    f32x4 acc = {0.f, 0.f, 0.f, 0.f};
#pragma unroll
    for (int kk = 0; kk < 8; kk++) {
      bf16x8 bh = *reinterpret_cast<const bf16x8*>(&canH[bbase + kk * 64]);
      bf16x8 bl = *reinterpret_cast<const bf16x8*>(&canL[bbase + kk * 64]);
      acc = __builtin_amdgcn_mfma_f32_16x16x32_bf16(ah[kk], bh, acc, 0, 0, 0);
      acc = __builtin_amdgcn_mfma_f32_16x16x32_bf16(al[kk], bh, acc, 0, 0, 0);
      acc = __builtin_amdgcn_mfma_f32_16x16x32_bf16(ah[kk], bl, acc, 0, 0, 0);
    }
    // C/D layout: col(t)=lane&15, row(q)=(lane>>4)*4+reg [R4-validated]
    float mk = mask_can[b * T_ + tt * 16 + lq];
#pragma unroll
    for (int r = 0; r < 4; r++) {
      float v = acc[r];
#pragma unroll
      for (int j = 0; j < NBINS; j++) {
        float d = v - mus[j];
        binacc[r][j] += mk * __expf(d * d * nis2[j]);
      }
    }
  }

  // reduce over the 16 t-cols (lq), then one atomic per (q,bin)
#pragma unroll
  for (int r = 0; r < 4; r++)
#pragma unroll
    for (int j = 0; j < NBINS; j++) {
      float v = binacc[r][j];
      v += __shfl_xor(v, 1);
      v += __shfl_xor(v, 2);
      v += __shfl_xor(v, 4);
      v += __shfl_xor(v, 8);
      binacc[r][j] = v;
    }
  if (lq == 0) {
#pragma unroll
    for (int r = 0; r < 4; r++) {
      int q = mtile * 16 + lk * 4 + r;
#pragma unroll
      for (int j = 0; j < NBINS; j++)
        atomicAdd(&psum[(outb * Q_ + q) * NBINS + j], binacc[r][j]);
    }
  }
}

// ---------------------------------------------------------------------------
// final_kernel (fast path): per-b. Absorbs log-pool (log/clip * word_atten *
// mask_hq, q-reduce) + W_att projection + masked softmax + tanh dense.
// ---------------------------------------------------------------------------
__global__ __launch_bounds__(256) void final_kernel(
    const float* __restrict__ rep, const float* __restrict__ rep_cur,
    const float* __restrict__ mask_session, const float* __restrict__ W_dense,
    const float* __restrict__ b_dense, const float* __restrict__ W_att,
    const float* __restrict__ b_att, const float* __restrict__ word_atten,
    const float* __restrict__ mask_hq, const float* __restrict__ psum,
    float* __restrict__ out) {
  __shared__ float lp[NB_ * Q_ * NBINS];  // 2816 f = 11.3 KB
  __shared__ float pooled_sm[NB_ * NBINS];
  __shared__ float qproj[D_];
  __shared__ float scores_sm[NB_];
  int b = blockIdx.x, tid = threadIdx.x;

  // log-pool: thread = (nb, q), 256 threads = 8x32 exactly
  {
    int nb = tid >> 5, q = tid & 31;
    int outb = b * NB_ + nb;
    float wa = word_atten[outb * Q_ + q] * mask_hq[outb * Q_ + q];
    const float* ps = &psum[(outb * Q_ + q) * NBINS];
#pragma unroll
    for (int j = 0; j < NBINS; j++)
      lp[(nb * Q_ + q) * NBINS + j] =
          logf(fmaxf(ps[j], 1e-10f)) * 0.01f * wa;
  }

  // W_att projection
  const float* rc = rep_cur + b * D_;
  float acc = b_att[tid];
  for (int k = 0; k < D_; k++) acc += rc[k] * W_att[k * D_ + tid];
  qproj[tid] = acc;
  __syncthreads();

  // pooled[nb][j] = sum_q lp
  if (tid < NB_ * NBINS) {
    int nb = tid / NBINS, j = tid - nb * NBINS;
    float s = 0.f;
#pragma unroll
    for (int q = 0; q < Q_; q++) s += lp[(nb * Q_ + q) * NBINS + j];
    pooled_sm[nb * NBINS + j] = s;
  }

  // attention scores
  int wv = tid >> 6, lane = tid & 63;
  for (int nn = wv; nn < NB_; nn += 4) {
    const float* rp = rep + ((size_t)b * NB_ + nn) * D_;
    float4 r4 = reinterpret_cast<const float4*>(rp)[lane];
    float4 q4 = *reinterpret_cast<float4*>(&qproj[lane * 4]);
    float s = r4.x * q4.x + r4.y * q4.y + r4.z * q4.z + r4.w * q4.w;
#pragma unroll
    for (int off = 32; off > 0; off >>= 1) s += __shfl_down(s, off);
    if (lane == 0) scores_sm[nn] = s * 0.0625f;  // 1/sqrt(256)
  }
  __syncthreads();

  if (tid == 0) {
    float sc[NB_];
    float mx = -1e30f;
    for (int nn = 0; nn < NB_; nn++) {
      float s = (mask_session[b * NB_ + nn] > 0.f) ? scores_sm[nn] : -1e9f;
      sc[nn] = s;
      mx = fmaxf(mx, s);
    }
    float den = 0.f;
    for (int nn = 0; nn < NB_; nn++) {
      sc[nn] = __expf(sc[nn] - mx);
      den += sc[nn];
    }
    float res = 0.f;
    for (int nn = 0; nn < NB_; nn++) {
      float ms = mask_session[b * NB_ + nn];
      float pw = b_dense[0];
      for (int j = 0; j < NBINS; j++)
        pw += pooled_sm[nn * NBINS + j] * ms * W_dense[j];
      res += tanhf(pw) * (sc[nn] / den);
    }
    out[b] = res;
  }
}

// ===========================================================================
// Fallback path (ws too small): R4's validated kernels, verbatim.
// ===========================================================================
__global__ __launch_bounds__(256) void pool_kernel_fb(
    const float* __restrict__ hq, const float* __restrict__ can,
    const float* __restrict__ word_atten, const float* __restrict__ mask_hq,
    const float* __restrict__ mask_can, float* __restrict__ pooled) {
  __shared__ __align__(16) ushort_t can_hi[32 * 264];
  __shared__ __align__(16) ushort_t can_lo[32 * 264];
  float* partial = (float*)can_hi;
  float* lp_sm = ((float*)can_hi) + 704;

  const float mus[NBINS] = {1.0f, 0.9f, 0.7f, 0.5f, 0.3f, 0.1f,
                            -0.1f, -0.3f, -0.5f, -0.7f, -0.9f};
  const float is2[NBINS] = {5.0e5f, 50.f, 50.f, 50.f, 50.f, 50.f,
                            50.f, 50.f, 50.f, 50.f, 50.f};

  int b = blockIdx.x & 63;
  int nb = blockIdx.x >> 6;
  int outb = b * NB_ + nb;
  int tid = threadIdx.x;
  int wv = tid >> 6, lane = tid & 63;
  int lq = lane & 15, lk = lane >> 4;
  int mtile = wv >> 1, ntile = wv & 1;

  const float* hq_base = hq + (size_t)outb * (Q_ * D_);
  const float* can_base = can + (size_t)b * (T_ * D_);
  const float* maskcan_b = mask_can + b * T_;

  const float* arow = hq_base + (size_t)(mtile * 16 + lq) * D_;
  float sumsq = 0.f;
#pragma unroll
  for (int kk = 0; kk < 8; kk++) {
    const float* p = arow + kk * 32 + lk * 8;
    float4 x = reinterpret_cast<const float4*>(p)[0];
    float4 y = reinterpret_cast<const float4*>(p)[1];
    sumsq += x.x * x.x + x.y * x.y + x.z * x.z + x.w * x.w +
             y.x * y.x + y.y * y.y + y.z * y.z + y.w * y.w;
  }
  sumsq += __shfl_xor(sumsq, 16);
  sumsq += __shfl_xor(sumsq, 32);
  float ainv = 1.0f / fmaxf(sqrtf(sumsq), 1e-10f);

  bf16x8 a_hi[8], a_lo[8];
#pragma unroll
  for (int kk = 0; kk < 8; kk++) {
    const float* p = arow + kk * 32 + lk * 8;
    float4 x = reinterpret_cast<const float4*>(p)[0];
    float4 y = reinterpret_cast<const float4*>(p)[1];
    float v[8] = {x.x, x.y, x.z, x.w, y.x, y.y, y.z, y.w};
    union { bf16x8 v8; ushort_t u[8]; } H, L;
#pragma unroll
    for (int j = 0; j < 8; j++) {
      float s = v[j] * ainv;
      ushort_t h = bf16_rnd(s);
      float hf = __uint_as_float(((uint_t)h) << 16);
      H.u[j] = h;
      L.u[j] = bf16_rnd(s - hf);
    }
    a_hi[kk] = H.v8;
    a_lo[kk] = L.v8;
  }

  float binacc[4][NBINS];
#pragma unroll
  for (int r = 0; r < 4; r++)
#pragma unroll
    for (int j = 0; j < NBINS; j++) binacc[r][j] = 0.0f;

  for (int ch = 0; ch < 8; ch++) {
    __syncthreads();
#pragma unroll
    for (int it = 0; it < 4; it++) {
      int flat = it * 2048 + tid * 8;
      int row = flat >> 8, col = flat & 255;
      int trow = ch * 32 + row;
      const float* src = can_base + (size_t)trow * D_ + col;
      float4 x = reinterpret_cast<const float4*>(src)[0];
      float4 y = reinterpret_cast<const float4*>(src)[1];
      float s = x.x * x.x + x.y * x.y + x.z * x.z + x.w * x.w +
                y.x * y.x + y.y * y.y + y.z * y.z + y.w * y.w;
      s += __shfl_xor(s, 1);
      s += __shfl_xor(s, 2);
      s += __shfl_xor(s, 4);
      s += __shfl_xor(s, 8);
      s += __shfl_xor(s, 16);
      float inv = 1.0f / fmaxf(sqrtf(s), 1e-10f);
      float v[8] = {x.x, x.y, x.z, x.w, y.x, y.y, y.z, y.w};
      ushort_t h[8], l[8];
#pragma unroll
      for (int j = 0; j < 8; j++) {
        float sv = v[j] * inv;
        h[j] = bf16_rnd(sv);
        float hf = __uint_as_float(((uint_t)h[j]) << 16);
        l[j] = bf16_rnd(sv - hf);
      }
      uint4 ph = {pack2(h[0], h[1]), pack2(h[2], h[3]), pack2(h[4], h[5]),
                  pack2(h[6], h[7])};
      uint4 pl = {pack2(l[0], l[1]), pack2(l[2], l[3]), pack2(l[4], l[5]),
                  pack2(l[6], l[7])};
      *reinterpret_cast<uint4*>(&can_hi[row * 264 + col]) = ph;
      *reinterpret_cast<uint4*>(&can_lo[row * 264 + col]) = pl;
    }
    __syncthreads();

    f32x4 acc = {0.f, 0.f, 0.f, 0.f};
    const ushort_t* Bhi = &can_hi[(ntile * 16 + lq) * 264];
    const ushort_t* Blo = &can_lo[(ntile * 16 + lq) * 264];
#pragma unroll
    for (int kk = 0; kk < 8; kk++) {
      int off = kk * 32 + lk * 8;
      bf16x8 bh = *reinterpret_cast<const bf16x8*>(Bhi + off);
      bf16x8 bl = *reinterpret_cast<const bf16x8*>(Blo + off);
      acc = __builtin_amdgcn_mfma_f32_16x16x32_bf16(a_hi[kk], bh, acc, 0, 0, 0);
      acc = __builtin_amdgcn_mfma_f32_16x16x32_bf16(a_lo[kk], bh, acc, 0, 0, 0);
      acc = __builtin_amdgcn_mfma_f32_16x16x32_bf16(a_hi[kk], bl, acc, 0, 0, 0);
    }

    int t0 = ch * 32 + ntile * 16 + lq;
    float mk = maskcan_b[t0];
#pragma unroll
    for (int r = 0; r < 4; r++) {
      float v0 = acc[r];
#pragma unroll
      for (int j = 0; j < NBINS; j++) {
        float d0 = v0 - mus[j];
        binacc[r][j] += mk * __expf(-d0 * d0 * is2[j]);
      }
    }
  }

  __syncthreads();

#pragma unroll
  for (int r = 0; r < 4; r++)
#pragma unroll
    for (int j = 0; j < NBINS; j++) {
      float v = binacc[r][j];
      v += __shfl_xor(v, 1);
      v += __shfl_xor(v, 2);
      v += __shfl_xor(v, 4);
      v += __shfl_xor(v, 8);
      binacc[r][j] = v;
    }
  if (lq == 0) {
#pragma unroll
    for (int r = 0; r < 4; r++)
#pragma unroll
      for (int j = 0; j < NBINS; j++)
        partial[(wv * 16 + lk * 4 + r) * NBINS + j] = binacc[r][j];
  }
  __syncthreads();

  for (int idx = tid; idx < Q_ * NBINS; idx += 256) {
    int q = idx / NBINS;
    int j = idx - q * NBINS;
    int mt = q >> 4, lr = q & 15;
    float sum = partial[((2 * mt) * 16 + lr) * NBINS + j] +
                partial[((2 * mt + 1) * 16 + lr) * NBINS + j];
    float wa = word_atten[outb * Q_ + q] * mask_hq[outb * Q_ + q];
    lp_sm[q * NBINS + j] = logf(fmaxf(sum, 1e-10f)) * 0.01f * wa;
  }
  __syncthreads();

  if (tid < NBINS) {
    float acc2 = 0.f;
#pragma unroll
    for (int q = 0; q < Q_; q++) acc2 += lp_sm[q * NBINS + tid];
    pooled[outb * NBINS + tid] = acc2;
  }
}

__global__ __launch_bounds__(256) void final_kernel_fb(
    const float* __restrict__ rep, const float* __restrict__ rep_cur,
    const float* __restrict__ mask_session, const float* __restrict__ W_dense,
    const float* __restrict__ b_dense, const float* __restrict__ W_att,
    const float* __restrict__ b_att, const float* __restrict__ pooled,
    float* __restrict__ out) {
  __shared__ float qproj[D_];
  __shared__ float scores_sm[NB_];
  int b = blockIdx.x, tid = threadIdx.x;

  const float* rc = rep_cur + b * D_;
  float acc = b_att[tid];
  for (int k = 0; k < D_; k++) acc += rc[k] * W_att[k * D_ + tid];
  qproj[tid] = acc;
  __syncthreads();

  int wv = tid >> 6, lane = tid & 63;
  for (int nn = wv; nn < NB_; nn += 4) {
    const float* rp = rep + ((size_t)b * NB_ + nn) * D_;
    float4 r4 = reinterpret_cast<const float4*>(rp)[lane];
    float4 q4 = *reinterpret_cast<float4*>(&qproj[lane * 4]);
    float s = r4.x * q4.x + r4.y * q4.y + r4.z * q4.z + r4.w * q4.w;
#pragma unroll
    for (int off = 32; off > 0; off >>= 1) s += __shfl_down(s, off);
    if (lane == 0) scores_sm[nn] = s * 0.0625f;
  }
  __syncthreads();

  if (tid == 0) {
    float sc[NB_];
    float mx = -1e30f;
    for (int nn = 0; nn < NB_; nn++) {
      float s = (mask_session[b * NB_ + nn] > 0.f) ? scores_sm[nn] : -1e9f;
      sc[nn] = s;
      mx = fmaxf(mx, s);
    }
    float den = 0.f;
    for (int nn = 0; nn < NB_; nn++) {
      sc[nn] = __expf(sc[nn] - mx);
      den += sc[nn];
    }
    float res = 0.f;
    for (int nn = 0; nn < NB_; nn++) {
      float ms = mask_session[b * NB_ + nn];
      float pw = b_dense[0];
      for (int j = 0; j < NBINS; j++)
        pw += pooled[(b * NB_ + nn) * NBINS + j] * ms * W_dense[j];
      res += tanhf(pw) * (sc[nn] / den);
    }
    out[b] = res;
  }
}

extern "C" void kernel_launch(void* const* d_in, const int* in_sizes, int n_in,
                              void* d_out, int out_size, void* d_ws,
                              size_t ws_size, hipStream_t stream) {
  const float* word_atten = (const float*)d_in[0];
  const float* hq = (const float*)d_in[1];
  const float* can = (const float*)d_in[2];
  const float* rep = (const float*)d_in[3];
  const float* rep_cur = (const float*)d_in[4];
  const float* mask_hq = (const float*)d_in[5];
  const float* mask_can = (const float*)d_in[6];
  const float* mask_session = (const float*)d_in[7];
  const float* W_dense = (const float*)d_in[8];
  const float* b_dense = (const float*)d_in[9];
  const float* W_att = (const float*)d_in[10];
  const float* b_att = (const float*)d_in[11];
  float* out = (float*)d_out;

  char* ws = (char*)d_ws;
  if (ws_size >= (size_t)WS_NEED) {
    uint4* canH = (uint4*)(ws + CANH_OFF);
    uint4* canL = (uint4*)(ws + CANL_OFF);
    uint4* hqH = (uint4*)(ws + HQH_OFF);
    uint4* hqL = (uint4*)(ws + HQL_OFF);
    float* psum = (float*)(ws + PSUM_OFF);

    hipMemsetAsync(psum, 0, (size_t)B_ * NB_ * Q_ * NBINS * sizeof(float),
                   stream);
    hipLaunchKernelGGL(split_kernel, dim3(1024), dim3(256), 0, stream, can, hq,
                       canH, canL, hqH, hqL);
    hipLaunchKernelGGL(pool_kernel, dim3(2048), dim3(256), 0, stream, canH,
                       canL, hqH, hqL, mask_can, psum);
    hipLaunchKernelGGL(final_kernel, dim3(B_), dim3(256), 0, stream, rep,
                       rep_cur, mask_session, W_dense, b_dense, W_att, b_att,
                       word_atten, mask_hq, psum, out);
  } else {
    float* pooled = (float*)ws;  // 22.5 KB
    hipLaunchKernelGGL(pool_kernel_fb, dim3(B_ * NB_), dim3(256), 0, stream,
                       hq, can, word_atten, mask_hq, mask_can, pooled);
    hipLaunchKernelGGL(final_kernel_fb, dim3(B_), dim3(256), 0, stream, rep,
                       rep_cur, mask_session, W_dense, b_dense, W_att, b_att,
                       pooled, out);
  }
}

// Round 6
// 151.611 us; speedup vs baseline: 1.3992x; 1.3992x over previous
//
#include <hip/hip_runtime.h>

#define B_ 64
#define NB_ 8
#define Q_ 32
#define T_ 256
#define D_ 256
#define NBINS 11

typedef __attribute__((ext_vector_type(8))) short bf16x8;
typedef __attribute__((ext_vector_type(4))) float f32x4;
typedef unsigned short ushort_t;
typedef unsigned int uint_t;

__device__ inline ushort_t bf16_rnd(float f) {
  uint_t u = __float_as_uint(f);
  return (ushort_t)((u + 0x8000u) >> 16);
}
__device__ inline uint_t pack2(ushort_t a, ushort_t b) {
  return (uint_t)a | ((uint_t)b << 16);
}

// ---------------------------------------------------------------------------
// pool_kernel: R4's validated LDS-reduce structure, t-split in half.
// Grid 1024 = th(2) x nb(8) x b(64); block = (outb, 128-t half): 4 chunks of
// 32 t, 2 barriers each (8 vs R4's 16), LDS 33.8 KB -> 4 blocks/CU resident
// (R4 had 2). Split-bf16 3-MFMA (~fp32 precision, R4-validated). Block writes
// NON-ATOMIC partial bin sums psum[outb][th][q*11+j] (R5 lesson: 720k global
// atomics = 45 MB memory-side write traffic + latency disaster).
// XCD swizzle: blockIdx%8 = b%8 for all (th, nb) of one b -> can[b] read once.
// ---------------------------------------------------------------------------
__global__ __launch_bounds__(256) void pool_kernel(
    const float* __restrict__ hq, const float* __restrict__ can,
    const float* __restrict__ mask_can, float* __restrict__ psum) {
  __shared__ __align__(16) ushort_t can_hi[32 * 264];  // 16896 B
  __shared__ __align__(16) ushort_t can_lo[32 * 264];  // 16896 B
  float* partial = (float*)can_hi;  // overlay after final barrier: 704 floats

  const float mus[NBINS] = {1.0f, 0.9f, 0.7f, 0.5f, 0.3f, 0.1f,
                            -0.1f, -0.3f, -0.5f, -0.7f, -0.9f};
  const float nis2[NBINS] = {-5.0e5f, -50.f, -50.f, -50.f, -50.f, -50.f,
                             -50.f, -50.f, -50.f, -50.f, -50.f};

  int i = blockIdx.x;
  int b = i & 63;          // XCD = i%8 = b%8
  int nb = (i >> 6) & 7;
  int th = i >> 9;         // 0/1: which 128-t half
  int outb = b * NB_ + nb;
  int tid = threadIdx.x;
  int wv = tid >> 6, lane = tid & 63;
  int lq = lane & 15, lk = lane >> 4;
  int mtile = wv >> 1, ntile = wv & 1;

  const float* hq_base = hq + (size_t)outb * (Q_ * D_);
  const float* can_base = can + (size_t)b * (T_ * D_);
  const float* maskcan_b = mask_can + b * T_;

  // ---- A fragments in registers, hi/lo split, inline row norm ----
  const float* arow = hq_base + (size_t)(mtile * 16 + lq) * D_;
  float sumsq = 0.f;
#pragma unroll
  for (int kk = 0; kk < 8; kk++) {
    const float* p = arow + kk * 32 + lk * 8;
    float4 x = reinterpret_cast<const float4*>(p)[0];
    float4 y = reinterpret_cast<const float4*>(p)[1];
    sumsq += x.x * x.x + x.y * x.y + x.z * x.z + x.w * x.w +
             y.x * y.x + y.y * y.y + y.z * y.z + y.w * y.w;
  }
  sumsq += __shfl_xor(sumsq, 16);
  sumsq += __shfl_xor(sumsq, 32);
  float ainv = 1.0f / fmaxf(sqrtf(sumsq), 1e-10f);

  bf16x8 a_hi[8], a_lo[8];
#pragma unroll
  for (int kk = 0; kk < 8; kk++) {
    const float* p = arow + kk * 32 + lk * 8;
    float4 x = reinterpret_cast<const float4*>(p)[0];
    float4 y = reinterpret_cast<const float4*>(p)[1];
    float v[8] = {x.x, x.y, x.z, x.w, y.x, y.y, y.z, y.w};
    union { bf16x8 v8; ushort_t u[8]; } H, L;
#pragma unroll
    for (int j = 0; j < 8; j++) {
      float s = v[j] * ainv;
      ushort_t h = bf16_rnd(s);
      float hf = __uint_as_float(((uint_t)h) << 16);
      H.u[j] = h;
      L.u[j] = bf16_rnd(s - hf);
    }
    a_hi[kk] = H.v8;
    a_lo[kk] = L.v8;
  }

  float binacc[4][NBINS];
#pragma unroll
  for (int r = 0; r < 4; r++)
#pragma unroll
    for (int j = 0; j < NBINS; j++) binacc[r][j] = 0.0f;

  for (int ch = 0; ch < 4; ch++) {
    __syncthreads();  // previous chunk fully consumed
    // ---- stage can chunk: 32 rows of this block's 128-t half ----
#pragma unroll
    for (int it = 0; it < 4; it++) {
      int flat = it * 2048 + tid * 8;
      int row = flat >> 8, col = flat & 255;
      int trow = th * 128 + ch * 32 + row;
      const float* src = can_base + (size_t)trow * D_ + col;
      float4 x = reinterpret_cast<const float4*>(src)[0];
      float4 y = reinterpret_cast<const float4*>(src)[1];
      float s = x.x * x.x + x.y * x.y + x.z * x.z + x.w * x.w +
                y.x * y.x + y.y * y.y + y.z * y.z + y.w * y.w;
      // 32 consecutive threads cover one 256-col row
      s += __shfl_xor(s, 1);
      s += __shfl_xor(s, 2);
      s += __shfl_xor(s, 4);
      s += __shfl_xor(s, 8);
      s += __shfl_xor(s, 16);
      float inv = 1.0f / fmaxf(sqrtf(s), 1e-10f);
      float v[8] = {x.x, x.y, x.z, x.w, y.x, y.y, y.z, y.w};
      ushort_t h[8], l[8];
#pragma unroll
      for (int j = 0; j < 8; j++) {
        float sv = v[j] * inv;
        h[j] = bf16_rnd(sv);
        float hf = __uint_as_float(((uint_t)h[j]) << 16);
        l[j] = bf16_rnd(sv - hf);
      }
      uint4 ph = {pack2(h[0], h[1]), pack2(h[2], h[3]), pack2(h[4], h[5]),
                  pack2(h[6], h[7])};
      uint4 pl = {pack2(l[0], l[1]), pack2(l[2], l[3]), pack2(l[4], l[5]),
                  pack2(l[6], l[7])};
      *reinterpret_cast<uint4*>(&can_hi[row * 264 + col]) = ph;
      *reinterpret_cast<uint4*>(&can_lo[row * 264 + col]) = pl;
    }
    __syncthreads();

    // ---- 3-MFMA split K-loop (one 16x16 tile per wave) ----
    f32x4 acc = {0.f, 0.f, 0.f, 0.f};
    const ushort_t* Bhi = &can_hi[(ntile * 16 + lq) * 264];
    const ushort_t* Blo = &can_lo[(ntile * 16 + lq) * 264];
#pragma unroll
    for (int kk = 0; kk < 8; kk++) {
      int off = kk * 32 + lk * 8;
      bf16x8 bh = *reinterpret_cast<const bf16x8*>(Bhi + off);
      bf16x8 bl = *reinterpret_cast<const bf16x8*>(Blo + off);
      acc = __builtin_amdgcn_mfma_f32_16x16x32_bf16(a_hi[kk], bh, acc, 0, 0, 0);
      acc = __builtin_amdgcn_mfma_f32_16x16x32_bf16(a_lo[kk], bh, acc, 0, 0, 0);
      acc = __builtin_amdgcn_mfma_f32_16x16x32_bf16(a_hi[kk], bl, acc, 0, 0, 0);
    }

    // ---- Gaussian bin pass on C fragment ----
    // C/D: col(t)=lane&15, row(q)=(lane>>4)*4+reg  [R4-validated]
    int t0 = th * 128 + ch * 32 + ntile * 16 + lq;
    float mk = maskcan_b[t0];
#pragma unroll
    for (int r = 0; r < 4; r++) {
      float v0 = acc[r];
#pragma unroll
      for (int j = 0; j < NBINS; j++) {
        float d0 = v0 - mus[j];
        binacc[r][j] += mk * __expf(d0 * d0 * nis2[j]);
      }
    }
  }

  __syncthreads();  // can_hi/lo dead; overlay reduction buffer

  // reduce over the 16 t-cols (lq) held by this wave
#pragma unroll
  for (int r = 0; r < 4; r++)
#pragma unroll
    for (int j = 0; j < NBINS; j++) {
      float v = binacc[r][j];
      v += __shfl_xor(v, 1);
      v += __shfl_xor(v, 2);
      v += __shfl_xor(v, 4);
      v += __shfl_xor(v, 8);
      binacc[r][j] = v;
    }
  if (lq == 0) {
#pragma unroll
    for (int r = 0; r < 4; r++)
#pragma unroll
      for (int j = 0; j < NBINS; j++)
        partial[(wv * 16 + lk * 4 + r) * NBINS + j] = binacc[r][j];
  }
  __syncthreads();

  // combine ntile halves; write partial bin sums (no log yet — other th
  // half is in another block). STRIDED over 352 items (R3 lesson).
  float* dst = &psum[(size_t)(outb * 2 + th) * (Q_ * NBINS)];
  for (int idx = tid; idx < Q_ * NBINS; idx += 256) {
    int q = idx / NBINS;
    int j = idx - q * NBINS;
    int mt = q >> 4, lr = q & 15;
    dst[idx] = partial[((2 * mt) * 16 + lr) * NBINS + j] +
               partial[((2 * mt + 1) * 16 + lr) * NBINS + j];
  }
}

// ---------------------------------------------------------------------------
// final_kernel: per-b. Combines th-halves, absorbs log-pool (log/clip *
// word_atten * mask_hq, q-reduce) + W_att projection + masked softmax +
// tanh dense.  (Structure validated in R5.)
// ---------------------------------------------------------------------------
__global__ __launch_bounds__(256) void final_kernel(
    const float* __restrict__ rep, const float* __restrict__ rep_cur,
    const float* __restrict__ mask_session, const float* __restrict__ W_dense,
    const float* __restrict__ b_dense, const float* __restrict__ W_att,
    const float* __restrict__ b_att, const float* __restrict__ word_atten,
    const float* __restrict__ mask_hq, const float* __restrict__ psum,
    float* __restrict__ out) {
  __shared__ float lp[NB_ * Q_ * NBINS];  // 2816 floats
  __shared__ float pooled_sm[NB_ * NBINS];
  __shared__ float qproj[D_];
  __shared__ float scores_sm[NB_];
  int b = blockIdx.x, tid = threadIdx.x;

  // log-pool: thread = (nb, q); 256 threads = 8 x 32 exactly
  {
    int nb = tid >> 5, q = tid & 31;
    int outb = b * NB_ + nb;
    float wa = word_atten[outb * Q_ + q] * mask_hq[outb * Q_ + q];
    const float* p0 = &psum[(size_t)(outb * 2 + 0) * (Q_ * NBINS) + q * NBINS];
    const float* p1 = &psum[(size_t)(outb * 2 + 1) * (Q_ * NBINS) + q * NBINS];
#pragma unroll
    for (int j = 0; j < NBINS; j++) {
      float s = p0[j] + p1[j];
      lp[(nb * Q_ + q) * NBINS + j] = logf(fmaxf(s, 1e-10f)) * 0.01f * wa;
    }
  }

  // W_att projection
  const float* rc = rep_cur + b * D_;
  float acc = b_att[tid];
  for (int k = 0; k < D_; k++) acc += rc[k] * W_att[k * D_ + tid];
  qproj[tid] = acc;
  __syncthreads();

  // pooled[nb][j] = sum_q lp
  if (tid < NB_ * NBINS) {
    int nb = tid / NBINS, j = tid - nb * NBINS;
    float s = 0.f;
#pragma unroll
    for (int q = 0; q < Q_; q++) s += lp[(nb * Q_ + q) * NBINS + j];
    pooled_sm[nb * NBINS + j] = s;
  }

  // attention scores
  int wv = tid >> 6, lane = tid & 63;
  for (int nn = wv; nn < NB_; nn += 4) {
    const float* rp = rep + ((size_t)b * NB_ + nn) * D_;
    float4 r4 = reinterpret_cast<const float4*>(rp)[lane];
    float4 q4 = *reinterpret_cast<float4*>(&qproj[lane * 4]);
    float s = r4.x * q4.x + r4.y * q4.y + r4.z * q4.z + r4.w * q4.w;
#pragma unroll
    for (int off = 32; off > 0; off >>= 1) s += __shfl_down(s, off);
    if (lane == 0) scores_sm[nn] = s * 0.0625f;  // 1/sqrt(256)
  }
  __syncthreads();

  if (tid == 0) {
    float sc[NB_];
    float mx = -1e30f;
    for (int nn = 0; nn < NB_; nn++) {
      float s = (mask_session[b * NB_ + nn] > 0.f) ? scores_sm[nn] : -1e9f;
      sc[nn] = s;
      mx = fmaxf(mx, s);
    }
    float den = 0.f;
    for (int nn = 0; nn < NB_; nn++) {
      sc[nn] = __expf(sc[nn] - mx);
      den += sc[nn];
    }
    float res = 0.f;
    for (int nn = 0; nn < NB_; nn++) {
      float ms = mask_session[b * NB_ + nn];
      float pw = b_dense[0];
      for (int j = 0; j < NBINS; j++)
        pw += pooled_sm[nn * NBINS + j] * ms * W_dense[j];
      res += tanhf(pw) * (sc[nn] / den);
    }
    out[b] = res;
  }
}

// ---------------------------------------------------------------------------
// ws (floats): psum[512 outb][2 th][352] = 1.44 MB, written once per pool
// block before final reads it — no memset, no atomics.
// ---------------------------------------------------------------------------
extern "C" void kernel_launch(void* const* d_in, const int* in_sizes, int n_in,
                              void* d_out, int out_size, void* d_ws,
                              size_t ws_size, hipStream_t stream) {
  const float* word_atten = (const float*)d_in[0];
  const float* hq = (const float*)d_in[1];
  const float* can = (const float*)d_in[2];
  const float* rep = (const float*)d_in[3];
  const float* rep_cur = (const float*)d_in[4];
  const float* mask_hq = (const float*)d_in[5];
  const float* mask_can = (const float*)d_in[6];
  const float* mask_session = (const float*)d_in[7];
  const float* W_dense = (const float*)d_in[8];
  const float* b_dense = (const float*)d_in[9];
  const float* W_att = (const float*)d_in[10];
  const float* b_att = (const float*)d_in[11];
  float* out = (float*)d_out;

  float* psum = (float*)d_ws;

  hipLaunchKernelGGL(pool_kernel, dim3(1024), dim3(256), 0, stream, hq, can,
                     mask_can, psum);
  hipLaunchKernelGGL(final_kernel, dim3(B_), dim3(256), 0, stream, rep,
                     rep_cur, mask_session, W_dense, b_dense, W_att, b_att,
                     word_atten, mask_hq, psum, out);
}

// Round 7
// 132.499 us; speedup vs baseline: 1.6010x; 1.1442x over previous
//
#include <hip/hip_runtime.h>

#define B_ 64
#define NB_ 8
#define Q_ 32
#define T_ 256
#define D_ 256
#define NBINS 11

typedef __attribute__((ext_vector_type(8))) short bf16x8;
typedef __attribute__((ext_vector_type(4))) float f32x4;
typedef unsigned short ushort_t;
typedef unsigned int uint_t;

// ws byte offsets: fragment-ordered bf16 hi/lo splits + psum
#define CANH_OFF 0u
#define CANL_OFF 8388608u
#define HQH_OFF 16777216u
#define HQL_OFF 25165824u
#define PSUM_OFF 33554432u

__device__ inline ushort_t bf16_rnd(float f) {
  uint_t u = __float_as_uint(f);
  return (ushort_t)((u + 0x8000u) >> 16);
}
__device__ inline uint_t pack2(ushort_t a, ushort_t b) {
  return (uint_t)a | ((uint_t)b << 16);
}

// ---------------------------------------------------------------------------
// split_kernel (R5-validated, verbatim): normalize rows, split fp32 ->
// (bf16 hi, bf16 lo), store in MFMA-fragment order:
//   frag(tile, kk) elem for lane l = X[tile*16+(l&15)][kk*32+(l>>4)*8+j].
// Blocks 0..511: can (b, 32-row chunk). Blocks 512..1023: hq (outb, 32 rows).
// The serial norm-shfl chains live HERE, in a 1024-block throughput kernel,
// not in the latency-critical pool kernel (R6 lesson).
// ---------------------------------------------------------------------------
__global__ __launch_bounds__(256) void split_kernel(
    const float* __restrict__ can, const float* __restrict__ hq,
    uint4* __restrict__ canH, uint4* __restrict__ canL,
    uint4* __restrict__ hqH, uint4* __restrict__ hqL) {
  __shared__ __align__(16) ushort_t sm_hi[32 * 264];
  __shared__ __align__(16) ushort_t sm_lo[32 * 264];
  int blk = blockIdx.x;
  int tid = threadIdx.x;
  const float* src;
  uint4 *dH, *dL;
  int tilebase;
  if (blk < 512) {
    int b = blk >> 3, ch = blk & 7;
    src = can + ((size_t)b * T_ + ch * 32) * D_;
    tilebase = b * 16 + ch * 2;
    dH = canH;
    dL = canL;
  } else {
    int outb = blk - 512;
    src = hq + (size_t)outb * Q_ * D_;
    tilebase = outb * 2;
    dH = hqH;
    dL = hqL;
  }
#pragma unroll
  for (int it = 0; it < 4; it++) {
    int flat = it * 2048 + tid * 8;
    int row = flat >> 8, col = flat & 255;
    const float* p = src + row * D_ + col;
    float4 x = reinterpret_cast<const float4*>(p)[0];
    float4 y = reinterpret_cast<const float4*>(p)[1];
    float s = x.x * x.x + x.y * x.y + x.z * x.z + x.w * x.w +
              y.x * y.x + y.y * y.y + y.z * y.z + y.w * y.w;
    // 32 consecutive threads cover one 256-col row
    s += __shfl_xor(s, 1);
    s += __shfl_xor(s, 2);
    s += __shfl_xor(s, 4);
    s += __shfl_xor(s, 8);
    s += __shfl_xor(s, 16);
    float inv = 1.0f / fmaxf(sqrtf(s), 1e-10f);
    float v[8] = {x.x, x.y, x.z, x.w, y.x, y.y, y.z, y.w};
    ushort_t h[8], l[8];
#pragma unroll
    for (int j = 0; j < 8; j++) {
      float sv = v[j] * inv;
      h[j] = bf16_rnd(sv);
      float hf = __uint_as_float(((uint_t)h[j]) << 16);
      l[j] = bf16_rnd(sv - hf);
    }
    uint4 ph = {pack2(h[0], h[1]), pack2(h[2], h[3]), pack2(h[4], h[5]),
                pack2(h[6], h[7])};
    uint4 pl = {pack2(l[0], l[1]), pack2(l[2], l[3]), pack2(l[4], l[5]),
                pack2(l[6], l[7])};
    *reinterpret_cast<uint4*>(&sm_hi[row * 264 + col]) = ph;
    *reinterpret_cast<uint4*>(&sm_lo[row * 264 + col]) = pl;
  }
  __syncthreads();
  int wv = tid >> 6, lane = tid & 63;
  int tl = wv >> 1, part = wv & 1;  // tile-local 0/1, hi/lo part
  int lq = lane & 15, lk = lane >> 4;
  const ushort_t* smp = part ? sm_lo : sm_hi;
  uint4* dst = part ? dL : dH;
#pragma unroll
  for (int kk = 0; kk < 8; kk++) {
    const ushort_t* a = &smp[(tl * 16 + lq) * 264 + kk * 32 + lk * 8];
    dst[((size_t)(tilebase + tl) * 8 + kk) * 64 + lane] =
        *reinterpret_cast<const uint4*>(a);
  }
}

// ---------------------------------------------------------------------------
// pool_kernel: grid 512 = (b 64, nb 8); block = 4 waves: wave w covers
// mtile = w&1 (16 q-rows) x tq = w>>1 (128-t half, 8 tiles of 16 t).
// Barrier-free, LDS-free main loop: A-frags (32 loads) + per-tile B-frags
// (16 loads) straight from fragment-ordered ws, all 16 B/lane coalesced.
// Deferred-bins pipeline: tile ti's loads are issued BEFORE the ~600-cyc bin
// pass of tile ti-1, hiding L2 latency with no double-buffer registers.
// Split-bf16 3-MFMA (R4-validated numerics). Epilogue: shfl-reduce over lq,
// 2.8 KB LDS partial exchange, single non-atomic psum write (R6-validated).
// XCD swizzle: blockIdx%8 = b%8.
// ---------------------------------------------------------------------------
__global__ __launch_bounds__(256, 2) void pool_kernel(
    const uint4* __restrict__ canH, const uint4* __restrict__ canL,
    const uint4* __restrict__ hqH, const uint4* __restrict__ hqL,
    const float* __restrict__ mask_can, float* __restrict__ psum) {
  __shared__ float partial[4 * 16 * NBINS];  // 2816 B

  const float mus[NBINS] = {1.0f, 0.9f, 0.7f, 0.5f, 0.3f, 0.1f,
                            -0.1f, -0.3f, -0.5f, -0.7f, -0.9f};
  const float nis2[NBINS] = {-5.0e5f, -50.f, -50.f, -50.f, -50.f, -50.f,
                             -50.f, -50.f, -50.f, -50.f, -50.f};

  int i = blockIdx.x;
  int b = i & 63;  // XCD = i%8 = b%8
  int nb = i >> 6;
  int outb = b * NB_ + nb;
  int tid = threadIdx.x;
  int wv = tid >> 6, lane = tid & 63;
  int lq = lane & 15, lk = lane >> 4;
  int mtile = wv & 1, tq = wv >> 1;

  // ---- A fragments: 16 coalesced 16B loads from ws ----
  bf16x8 ah[8], al[8];
  {
    size_t abase = (size_t)(outb * 2 + mtile) * 8 * 64 + lane;
#pragma unroll
    for (int kk = 0; kk < 8; kk++) {
      ah[kk] = *reinterpret_cast<const bf16x8*>(&hqH[abase + kk * 64]);
      al[kk] = *reinterpret_cast<const bf16x8*>(&hqL[abase + kk * 64]);
    }
  }

  float binacc[4][NBINS];
#pragma unroll
  for (int r = 0; r < 4; r++)
#pragma unroll
    for (int j = 0; j < NBINS; j++) binacc[r][j] = 0.0f;

  f32x4 accPrev;
  float mkPrev = 0.0f;

  // ---- tile 0 ----
  {
    int tt = tq * 8;
    size_t bbase = (size_t)(b * 16 + tt) * 8 * 64 + lane;
    f32x4 acc = {0.f, 0.f, 0.f, 0.f};
#pragma unroll
    for (int kk = 0; kk < 8; kk++) {
      bf16x8 bh = *reinterpret_cast<const bf16x8*>(&canH[bbase + kk * 64]);
      bf16x8 bl = *reinterpret_cast<const bf16x8*>(&canL[bbase + kk * 64]);
      acc = __builtin_amdgcn_mfma_f32_16x16x32_bf16(ah[kk], bh, acc, 0, 0, 0);
      acc = __builtin_amdgcn_mfma_f32_16x16x32_bf16(al[kk], bh, acc, 0, 0, 0);
      acc = __builtin_amdgcn_mfma_f32_16x16x32_bf16(ah[kk], bl, acc, 0, 0, 0);
    }
    accPrev = acc;
    mkPrev = mask_can[b * T_ + tt * 16 + lq];
  }

  // ---- tiles 1..7: load(ti) issued before bins(ti-1) ----
  for (int ti = 1; ti < 8; ti++) {
    int tt = tq * 8 + ti;
    size_t bbase = (size_t)(b * 16 + tt) * 8 * 64 + lane;
    bf16x8 bh[8], bl[8];
#pragma unroll
    for (int kk = 0; kk < 8; kk++) {
      bh[kk] = *reinterpret_cast<const bf16x8*>(&canH[bbase + kk * 64]);
      bl[kk] = *reinterpret_cast<const bf16x8*>(&canL[bbase + kk * 64]);
    }
    // bins of previous tile — no dependence on the loads above, so the
    // compiler schedules them under the outstanding vmcnt.
    // C/D: col(t)=lane&15, row(q)=(lane>>4)*4+reg  [R4-validated]
#pragma unroll
    for (int r = 0; r < 4; r++) {
      float v0 = accPrev[r];
#pragma unroll
      for (int j = 0; j < NBINS; j++) {
        float d0 = v0 - mus[j];
        binacc[r][j] += mkPrev * __expf(d0 * d0 * nis2[j]);
      }
    }
    f32x4 acc = {0.f, 0.f, 0.f, 0.f};
#pragma unroll
    for (int kk = 0; kk < 8; kk++) {
      acc = __builtin_amdgcn_mfma_f32_16x16x32_bf16(ah[kk], bh[kk], acc, 0, 0, 0);
      acc = __builtin_amdgcn_mfma_f32_16x16x32_bf16(al[kk], bh[kk], acc, 0, 0, 0);
      acc = __builtin_amdgcn_mfma_f32_16x16x32_bf16(ah[kk], bl[kk], acc, 0, 0, 0);
    }
    accPrev = acc;
    mkPrev = mask_can[b * T_ + tt * 16 + lq];
  }
  // bins of last tile
#pragma unroll
  for (int r = 0; r < 4; r++) {
    float v0 = accPrev[r];
#pragma unroll
    for (int j = 0; j < NBINS; j++) {
      float d0 = v0 - mus[j];
      binacc[r][j] += mkPrev * __expf(d0 * d0 * nis2[j]);
    }
  }

  // ---- reduce over the 16 t-cols (lq) held by this wave ----
#pragma unroll
  for (int r = 0; r < 4; r++)
#pragma unroll
    for (int j = 0; j < NBINS; j++) {
      float v = binacc[r][j];
      v += __shfl_xor(v, 1);
      v += __shfl_xor(v, 2);
      v += __shfl_xor(v, 4);
      v += __shfl_xor(v, 8);
      binacc[r][j] = v;
    }
  if (lq == 0) {
#pragma unroll
    for (int r = 0; r < 4; r++)
#pragma unroll
      for (int j = 0; j < NBINS; j++)
        partial[(wv * 16 + lk * 4 + r) * NBINS + j] = binacc[r][j];
  }
  __syncthreads();

  // combine tq halves (wave m and wave 2+m share mtile m); write psum once.
  // STRIDED over 352 items (R3 lesson).
  float* dst = &psum[(size_t)outb * (Q_ * NBINS)];
  for (int idx = tid; idx < Q_ * NBINS; idx += 256) {
    int q = idx / NBINS;
    int j = idx - q * NBINS;
    int m = q >> 4, r16 = q & 15;
    dst[idx] = partial[(m * 16 + r16) * NBINS + j] +
               partial[((2 + m) * 16 + r16) * NBINS + j];
  }
}

// ---------------------------------------------------------------------------
// final_kernel: per-b. Absorbs log-pool (log/clip * word_atten * mask_hq,
// q-reduce) + W_att projection + masked softmax + tanh dense. (R6-validated,
// psum now single-slice.)
// ---------------------------------------------------------------------------
__global__ __launch_bounds__(256) void final_kernel(
    const float* __restrict__ rep, const float* __restrict__ rep_cur,
    const float* __restrict__ mask_session, const float* __restrict__ W_dense,
    const float* __restrict__ b_dense, const float* __restrict__ W_att,
    const float* __restrict__ b_att, const float* __restrict__ word_atten,
    const float* __restrict__ mask_hq, const float* __restrict__ psum,
    float* __restrict__ out) {
  __shared__ float lp[NB_ * Q_ * NBINS];  // 2816 floats
  __shared__ float pooled_sm[NB_ * NBINS];
  __shared__ float qproj[D_];
  __shared__ float scores_sm[NB_];
  int b = blockIdx.x, tid = threadIdx.x;

  // log-pool: thread = (nb, q); 256 threads = 8 x 32 exactly
  {
    int nb = tid >> 5, q = tid & 31;
    int outb = b * NB_ + nb;
    float wa = word_atten[outb * Q_ + q] * mask_hq[outb * Q_ + q];
    const float* ps = &psum[(size_t)outb * (Q_ * NBINS) + q * NBINS];
#pragma unroll
    for (int j = 0; j < NBINS; j++)
      lp[(nb * Q_ + q) * NBINS + j] = logf(fmaxf(ps[j], 1e-10f)) * 0.01f * wa;
  }

  // W_att projection
  const float* rc = rep_cur + b * D_;
  float acc = b_att[tid];
  for (int k = 0; k < D_; k++) acc += rc[k] * W_att[k * D_ + tid];
  qproj[tid] = acc;
  __syncthreads();

  // pooled[nb][j] = sum_q lp
  if (tid < NB_ * NBINS) {
    int nb = tid / NBINS, j = tid - nb * NBINS;
    float s = 0.f;
#pragma unroll
    for (int q = 0; q < Q_; q++) s += lp[(nb * Q_ + q) * NBINS + j];
    pooled_sm[nb * NBINS + j] = s;
  }

  // attention scores
  int wv = tid >> 6, lane = tid & 63;
  for (int nn = wv; nn < NB_; nn += 4) {
    const float* rp = rep + ((size_t)b * NB_ + nn) * D_;
    float4 r4 = reinterpret_cast<const float4*>(rp)[lane];
    float4 q4 = *reinterpret_cast<float4*>(&qproj[lane * 4]);
    float s = r4.x * q4.x + r4.y * q4.y + r4.z * q4.z + r4.w * q4.w;
#pragma unroll
    for (int off = 32; off > 0; off >>= 1) s += __shfl_down(s, off);
    if (lane == 0) scores_sm[nn] = s * 0.0625f;  // 1/sqrt(256)
  }
  __syncthreads();

  if (tid == 0) {
    float sc[NB_];
    float mx = -1e30f;
    for (int nn = 0; nn < NB_; nn++) {
      float s = (mask_session[b * NB_ + nn] > 0.f) ? scores_sm[nn] : -1e9f;
      sc[nn] = s;
      mx = fmaxf(mx, s);
    }
    float den = 0.f;
    for (int nn = 0; nn < NB_; nn++) {
      sc[nn] = __expf(sc[nn] - mx);
      den += sc[nn];
    }
    float res = 0.f;
    for (int nn = 0; nn < NB_; nn++) {
      float ms = mask_session[b * NB_ + nn];
      float pw = b_dense[0];
      for (int j = 0; j < NBINS; j++)
        pw += pooled_sm[nn * NBINS + j] * ms * W_dense[j];
      res += tanhf(pw) * (sc[nn] / den);
    }
    out[b] = res;
  }
}

// ---------------------------------------------------------------------------
// ws: canH/canL/hqH/hqL (fragment-ordered bf16 splits, 33.5 MB) + psum
// (512 x 352 f, written once per pool block). ws_size >= 34.3 MB confirmed
// in R5 (fast path executed).
// ---------------------------------------------------------------------------
extern "C" void kernel_launch(void* const* d_in, const int* in_sizes, int n_in,
                              void* d_out, int out_size, void* d_ws,
                              size_t ws_size, hipStream_t stream) {
  const float* word_atten = (const float*)d_in[0];
  const float* hq = (const float*)d_in[1];
  const float* can = (const float*)d_in[2];
  const float* rep = (const float*)d_in[3];
  const float* rep_cur = (const float*)d_in[4];
  const float* mask_hq = (const float*)d_in[5];
  const float* mask_can = (const float*)d_in[6];
  const float* mask_session = (const float*)d_in[7];
  const float* W_dense = (const float*)d_in[8];
  const float* b_dense = (const float*)d_in[9];
  const float* W_att = (const float*)d_in[10];
  const float* b_att = (const float*)d_in[11];
  float* out = (float*)d_out;

  char* ws = (char*)d_ws;
  uint4* canH = (uint4*)(ws + CANH_OFF);
  uint4* canL = (uint4*)(ws + CANL_OFF);
  uint4* hqH = (uint4*)(ws + HQH_OFF);
  uint4* hqL = (uint4*)(ws + HQL_OFF);
  float* psum = (float*)(ws + PSUM_OFF);

  hipLaunchKernelGGL(split_kernel, dim3(1024), dim3(256), 0, stream, can, hq,
                     canH, canL, hqH, hqL);
  hipLaunchKernelGGL(pool_kernel, dim3(B_ * NB_), dim3(256), 0, stream, canH,
                     canL, hqH, hqL, mask_can, psum);
  hipLaunchKernelGGL(final_kernel, dim3(B_), dim3(256), 0, stream, rep,
                     rep_cur, mask_session, W_dense, b_dense, W_att, b_att,
                     word_atten, mask_hq, psum, out);
}